// Round 6
// baseline (101.148 us; speedup 1.0000x reference)
//
#include <hip/hip_runtime.h>
#include <stdint.h>

#define NB 16
#define NN 25200
#define NCLS 80
#define NROW 85
#define KPRE 1000
#define MAXDET 300
#define CONF_T 0.25f
#define IOU_T 0.45f
#define GCAP 4096

typedef unsigned long long u64;
typedef unsigned int u32;
typedef unsigned char u8;

// Descending-order sortable key: higher score -> smaller key; ties by index.
__device__ __forceinline__ u32 desc_key(float s) {
  u32 u = __float_as_uint(s);
  u = (u & 0x80000000u) ? ~u : (u | 0x80000000u);
  return ~u;
}
__device__ __forceinline__ float inv_key(u32 k) {
  u32 u = ~k;
  u32 o = (u & 0x80000000u) ? (u & 0x7fffffffu) : ~u;
  return __uint_as_float(o);
}

// ---------------- Kernel 0: zero the global histograms ----------------
__global__ __launch_bounds__(1024) void k_zero(u32* __restrict__ gHist) {
  gHist[blockIdx.x * 1024 + threadIdx.x] = 0;
}

// ------- Kernel 1: decode (LDS-staged coalesced) + fused histogram -------
// Grid (99, NB): block handles 256 rows of ONE image (last block partial).
__global__ __launch_bounds__(256) void k_decode(
    const float* __restrict__ pred, float* __restrict__ scores,
    int* __restrict__ clsArr, float4* __restrict__ boxes,
    u32* __restrict__ gHist) {
  __shared__ __align__(16) float lds[4][1360];
  __shared__ u32 h[4096];
  const int tid = threadIdx.x;
  const int wid = tid >> 6, lane = tid & 63;
  const int q = lane & 3, rl = lane >> 2;
  const int img = blockIdx.y;
  const u32 INVB = desc_key(-1.0f) >> 20;
  for (int t = tid; t < 4096; t += 256) h[t] = 0;
  float* L = lds[wid];
  const float* base = pred + (size_t)img * NN * NROW;
  const int waveRow0 = blockIdx.x * 256 + wid * 64;
  const int IMGF = NN * NROW;  // floats in one image
  __syncthreads();
  for (int c = 0; c < 4; ++c) {
    const int row0 = waveRow0 + c * 16;
    const int fbase = row0 * NROW;
#pragma unroll
    for (int k = 0; k < 5; ++k) {
      int off = k * 256 + lane * 4;
      int src = (fbase + off + 4 <= IMGF) ? (fbase + off) : 0;  // clamp OOB
      float4 v;
      __builtin_memcpy(&v, base + src, 16);
      *(float4*)(L + off) = v;
    }
    if (lane < 20) {
      int off = 1280 + lane * 4;
      int src = (fbase + off + 4 <= IMGF) ? (fbase + off) : 0;
      float4 v;
      __builtin_memcpy(&v, base + src, 16);
      *(float4*)(L + off) = v;
    }
    __syncthreads();
    const int row = row0 + rl;
    const bool rowOK = (row < NN);
    const float* R = L + rl * 85;
    float obj = R[4];
    float best = -1.0f;
    int bj = 0;
    const int j0 = q * 20;
#pragma unroll
    for (int jj = 0; jj < 20; ++jj) {
      float v = __fmul_rn(R[5 + j0 + jj], obj);
      if (v > best) { best = v; bj = j0 + jj; }
    }
#pragma unroll
    for (int d = 1; d < 4; d <<= 1) {
      float b2 = __shfl_xor(best, d, 64);
      int j2 = __shfl_xor(bj, d, 64);
      if (b2 > best || (b2 == best && j2 < bj)) { best = b2; bj = j2; }
    }
    bool valid = (best > CONF_T);
    // fused histogram: invalid rows wave-aggregated, valid rows one LDS atomic
    u64 bb = __ballot(q == 0 && rowOK && !valid);
    if (lane == 0 && bb) atomicAdd(&h[INVB], (u32)__popcll(bb));
    if (q == 0 && rowOK) {
      if (valid) atomicAdd(&h[desc_key(best) >> 20], 1u);
      int gid = img * NN + row;
      float x = R[0], y = R[1], w = R[2], hgt = R[3];
      float hx = __fmul_rn(w, 0.5f), hy = __fmul_rn(hgt, 0.5f);
      float4 bx;
      bx.x = __fsub_rn(x, hx);
      bx.y = __fsub_rn(y, hy);
      bx.z = __fadd_rn(x, hx);
      bx.w = __fadd_rn(y, hy);
      scores[gid] = valid ? best : -1.0f;
      clsArr[gid] = bj;
      boxes[gid] = bx;
    }
    __syncthreads();
  }
  // flush block-local histogram (few nonzero buckets)
  for (int t = tid; t < 4096; t += 256) {
    u32 v = h[t];
    if (v) atomicAdd(&gHist[img * 4096 + t], v);
  }
}

// ---------------- Kernel 2: select + per-class NMS + output ----------------
__global__ __launch_bounds__(1024) void k_select_nms(
    const float* __restrict__ scores, const int* __restrict__ clsArr,
    const float4* __restrict__ boxes, const u32* __restrict__ gHist,
    float* __restrict__ out) {
  const int img = blockIdx.x;
  const int tid = threadIdx.x;
  const int lane = tid & 63;
  const float* sc = scores + (size_t)img * NN;
  const size_t imgN = (size_t)img * NN;

  extern __shared__ __align__(16) char smem[];
  u64* buf = (u64*)smem;                // 32768 B (GCAP u64)
  float* bX1 = (float*)(smem + 32768);  // 4 x 4000 B
  float* bY1 = bX1 + KPRE;
  float* bX2 = bY1 + KPRE;
  float* bY2 = bX2 + KPRE;
  // tail of buf (bytes 8192..32767) reused AFTER phase D (only buf[0..999] live)
  char* tail = smem + 8192;
  u64* cb = (u64*)tail;                  // 80*16 u64 = 10240 B class bitmaps
  u32* s2 = (u32*)(tail + 10240);        // 1024 u32
  u32* clsL = (u32*)(tail + 14336);      // 1000 u32
  u8* alive = (u8*)(tail + 18336);       // 1024 u8
  int* clsStart = (int*)(tail + 19360);  // 81 int
  __shared__ u32 subhist[256];
  __shared__ u32 sB, sKr, sCnt, sThr;
  __shared__ u64 aliveW[16];
  __shared__ int wPre[16];

  // ---- Phase P: prefetch all keys into registers (one latency) ----
  u32 kk[25];
#pragma unroll
  for (int t = 0; t < 25; ++t) {
    int n = tid + t * 1024;
    kk[t] = (n < NN) ? desc_key(sc[n]) : 0xFFFFFFFFu;
  }

  // ---- Phase A: load global hist, block prefix-scan, find bucket B ----
  u32 h0 = gHist[img * 4096 + tid * 4 + 0];
  u32 h1 = gHist[img * 4096 + tid * 4 + 1];
  u32 h2 = gHist[img * 4096 + tid * 4 + 2];
  u32 h3 = gHist[img * 4096 + tid * 4 + 3];
  u32 s4 = h0 + h1 + h2 + h3;
  u32* scan = (u32*)buf;
  scan[tid] = s4;
  __syncthreads();
  for (int o = 1; o < 1024; o <<= 1) {
    u32 add = (tid >= o) ? scan[tid - o] : 0;
    __syncthreads();
    scan[tid] += add;
    __syncthreads();
  }
  u32 P = scan[tid] - s4;  // exclusive prefix of this 4-bucket group
  if (P < KPRE && P + s4 >= KPRE) {
    u32 cacc = P;
    u32 b = 3;
    if (cacc + h0 >= KPRE) b = 0;
    else {
      cacc += h0;
      if (cacc + h1 >= KPRE) b = 1;
      else {
        cacc += h1;
        if (cacc + h2 >= KPRE) b = 2;
        else cacc += h2;
      }
    }
    sB = tid * 4 + b;
    sKr = KPRE - cacc;  // entries still needed inside bucket B (>=1)
    sCnt = 0;
  }
  __syncthreads();
  const u32 B = sB;
  const u32 Kr = sKr;

  // ---- Phase A2: 8-bit sub-histogram (bits 19..12) of bucket-B keys ----
  if (tid < 256) subhist[tid] = 0;
  __syncthreads();
#pragma unroll
  for (int t = 0; t < 25; ++t)
    if ((kk[t] >> 20) == B) atomicAdd(&subhist[(kk[t] >> 12) & 255], 1u);
  __syncthreads();
  u32 myc = (tid < 256) ? subhist[tid] : 0;
  for (int o = 1; o < 256; o <<= 1) {
    u32 add = (tid < 256 && tid >= o) ? subhist[tid - o] : 0;
    __syncthreads();
    if (tid < 256) subhist[tid] += add;
    __syncthreads();
  }
  if (tid < 256) {
    u32 inc = subhist[tid], exc = inc - myc;
    if (exc < Kr && inc >= Kr) sThr = (B << 8) | (u32)tid;  // 20-bit threshold
  }
  __syncthreads();
  const u32 thr = sThr;

  // ---- Phase C: gather keys with (k>>12) <= thr (wave-aggregated) ----
#pragma unroll
  for (int t = 0; t < 25; ++t) {
    bool g = (kk[t] >> 12) <= thr;
    u64 bb = __ballot(g);
    if (bb) {
      int ldr = __ffsll((long long)bb) - 1;
      u32 base = 0;
      if (lane == ldr) base = atomicAdd(&sCnt, (u32)__popcll(bb));
      base = __shfl(base, ldr, 64);
      if (g) {
        u32 pos = base + (u32)__popcll(bb & ((1ull << lane) - 1ull));
        if (pos < GCAP) buf[pos] = ((u64)kk[t] << 32) | (u32)(tid + t * 1024);
      }
    }
  }
  __syncthreads();
  u32 cnt = sCnt < GCAP ? sCnt : GCAP;  // expected ~= KPRE + few ties
  u32 M = 1024;
  while (M < cnt) M <<= 1;
  for (u32 i = cnt + tid; i < M; i += 1024) buf[i] = ~0ull;
  __syncthreads();

  // ---- Phase D: bitonic sort ascending (usually M=1024) ----
  for (u32 k = 2; k <= M; k <<= 1) {
    for (u32 j = k >> 1; j > 0; j >>= 1) {
      for (u32 i = tid; i < M; i += 1024) {
        u32 l = i ^ j;
        if (l > i) {
          u64 a = buf[i], b = buf[l];
          bool asc = ((i & k) == 0);
          if (asc ? (a > b) : (a < b)) { buf[i] = b; buf[l] = a; }
        }
      }
      __syncthreads();
    }
  }

  // ---- Phase E: fetch winners into LDS SoA; zero class bitmaps ----
  if (tid < KPRE) {
    u32 n = (u32)buf[tid];
    int c = clsArr[imgN + n];
    float4 bx = boxes[imgN + n];
    bX1[tid] = bx.x; bY1[tid] = bx.y; bX2[tid] = bx.z; bY2[tid] = bx.w;
    clsL[tid] = (u32)c;
    alive[tid] = (inv_key((u32)(buf[tid] >> 32)) > CONF_T) ? 1 : 0;
  } else {
    alive[tid] = 0;
  }
  for (int t = tid; t < NCLS * 16; t += 1024) cb[t] = 0;
  __syncthreads();

  // ---- Phase F: class grouping via bitmaps + counting scatter ----
  if (tid < KPRE) atomicOr(&cb[clsL[tid] * 16 + (tid >> 6)], 1ull << (tid & 63));
  __syncthreads();
  if (tid < NCLS) {
    int s = 0;
#pragma unroll
    for (int w = 0; w < 16; ++w) s += (int)__popcll(cb[tid * 16 + w]);
    subhist[tid] = (u32)s;  // class counts (subhist free now)
  }
  __syncthreads();
  if (tid == 0) {
    int acc = 0;
    for (int c = 0; c < NCLS; ++c) { clsStart[c] = acc; acc += (int)subhist[c]; }
    clsStart[NCLS] = acc;
  }
  __syncthreads();
  if (tid < KPRE) {
    int c = (int)clsL[tid];
    int w = tid >> 6;
    int p = clsStart[c];
    for (int w2 = 0; w2 < w; ++w2) p += (int)__popcll(cb[c * 16 + w2]);
    p += (int)__popcll(cb[c * 16 + w] & ((1ull << (tid & 63)) - 1ull));
    s2[p] = (u32)tid;
  }
  __syncthreads();

  // ---- Phase H: per-class sequential greedy NMS (one wave per class) ----
  {
    const int wid2 = tid >> 6;
    for (int c = wid2; c < NCLS; c += 16) {
      int s = clsStart[c], e = clsStart[c + 1];
      float offc = __fmul_rn((float)c, 4096.0f);
      for (int i = s; i < e; ++i) {
        int ti = (int)s2[i];
        if (!alive[ti]) continue;  // wave-uniform
        float ix1 = __fadd_rn(bX1[ti], offc), iy1 = __fadd_rn(bY1[ti], offc);
        float ix2 = __fadd_rn(bX2[ti], offc), iy2 = __fadd_rn(bY2[ti], offc);
        float ia = __fmul_rn(__fsub_rn(ix2, ix1), __fsub_rn(iy2, iy1));
        for (int jb = i + 1 + lane; jb < e; jb += 64) {
          int tj = (int)s2[jb];
          float jx1 = __fadd_rn(bX1[tj], offc), jy1 = __fadd_rn(bY1[tj], offc);
          float jx2 = __fadd_rn(bX2[tj], offc), jy2 = __fadd_rn(bY2[tj], offc);
          float ja = __fmul_rn(__fsub_rn(jx2, jx1), __fsub_rn(jy2, jy1));
          float xx1 = fmaxf(ix1, jx1), yy1 = fmaxf(iy1, jy1);
          float xx2 = fminf(ix2, jx2), yy2 = fminf(iy2, jy2);
          float ww = fmaxf(__fsub_rn(xx2, xx1), 0.0f);
          float hh = fmaxf(__fsub_rn(yy2, yy1), 0.0f);
          float inter = __fmul_rn(ww, hh);
          float den = __fadd_rn(__fsub_rn(__fadd_rn(ia, ja), inter), 1e-9f);
          if (inter > __fmul_rn(IOU_T, den)) alive[tj] = 0;
        }
      }
    }
  }
  __syncthreads();

  // ---- Phase I: rank + write output ----
  float* outImg = out + (size_t)img * MAXDET * 6;
  for (int t = tid; t < MAXDET * 6; t += 1024) outImg[t] = 0.0f;
  if (tid < 64) {
#pragma unroll
    for (int g = 0; g < 16; ++g) {
      u64 w = __ballot(alive[g * 64 + lane] != 0);
      if (lane == 0) aliveW[g] = w;
    }
  }
  __syncthreads();
  if (tid == 0) {
    int cacc = 0;
    for (int w = 0; w < 16; ++w) { wPre[w] = cacc; cacc += __popcll(aliveW[w]); }
  }
  __syncthreads();
  if (tid < KPRE) {
    int w = tid >> 6, b = tid & 63;
    u64 aw = aliveW[w];
    if ((aw >> b) & 1ull) {
      u64 lm = b ? (~0ull >> (64 - b)) : 0ull;
      int rank = wPre[w] + __popcll(aw & lm);
      if (rank < MAXDET) {
        float* o = outImg + (size_t)rank * 6;
        o[0] = bX1[tid];
        o[1] = bY1[tid];
        o[2] = bX2[tid];
        o[3] = bY2[tid];
        o[4] = inv_key((u32)(buf[tid] >> 32));
        o[5] = (float)clsL[tid];
      }
    }
  }
}

extern "C" void kernel_launch(void* const* d_in, const int* in_sizes, int n_in,
                              void* d_out, int out_size, void* d_ws, size_t ws_size,
                              hipStream_t stream) {
  const float* pred = (const float*)d_in[0];
  char* ws = (char*)d_ws;
  size_t off = 0;
  float* scores = (float*)(ws + off); off += (size_t)NB * NN * 4;
  int* clsArr = (int*)(ws + off); off += (size_t)NB * NN * 4;
  float4* boxes = (float4*)(ws + off); off += (size_t)NB * NN * 16;
  u32* gHist = (u32*)(ws + off); off += (size_t)NB * 4096 * 4;
  if (off > ws_size) return;

  float* outp = (float*)d_out;
  k_zero<<<NB * 4096 / 1024, 1024, 0, stream>>>(gHist);
  dim3 gridD((NN + 255) / 256, NB);
  k_decode<<<gridD, 256, 0, stream>>>(pred, scores, clsArr, boxes, gHist);
  k_select_nms<<<NB, 1024, 48768, stream>>>(scores, clsArr, boxes, gHist, outp);
}